// Round 8
// baseline (419.671 us; speedup 1.0000x reference)
//
#include <hip/hip_runtime.h>
#include <math.h>

#define NEG_INF -10000.0f

typedef short bf16x8 __attribute__((ext_vector_type(8)));
typedef float f32x4 __attribute__((ext_vector_type(4)));

static constexpr int Dm = 256;   // model dim
static constexpr int Lm = 256;   // residues
static constexpr int Sm = 128;   // sequences
static constexpr int Mrows = Sm * Lm;  // 32768
static constexpr size_t HB = (size_t)Mrows * 32;  // head-plane stride (elems)

__device__ __forceinline__ ushort f2bf(float x) {
    unsigned u = __float_as_uint(x);
    unsigned r = (u + 0x7FFFu + ((u >> 16) & 1u)) >> 16;
    return (ushort)r;
}
__device__ __forceinline__ float bf2f(ushort h) {
    return __uint_as_float(((unsigned)h) << 16);
}
__device__ __forceinline__ void gload_lds16(const void* g, void* l) {
    __builtin_amdgcn_global_load_lds((__attribute__((address_space(1))) void*)g,
                                     (__attribute__((address_space(3))) void*)l,
                                     16, 0, 0);
}
__device__ __forceinline__ f32x4 mfma16(bf16x8 a, bf16x8 b, f32x4 c) {
    return __builtin_amdgcn_mfma_f32_16x16x32_bf16(a, b, c, 0, 0, 0);
}

// ---------------------------------------------------------------------------
// LayerNorm stats: one wave per row -> (mu, rsqrt(var+eps))
// ---------------------------------------------------------------------------
__global__ __launch_bounds__(256)
void ln_stats(const float* __restrict__ m, float* __restrict__ stats) {
    const int wid = threadIdx.x >> 6, lane = threadIdx.x & 63;
    const int row = (blockIdx.x << 2) + wid;
    const float4 a = ((const float4*)(m + (size_t)row * Dm))[lane];
    float s  = a.x + a.y + a.z + a.w;
    float ss = a.x*a.x + a.y*a.y + a.z*a.z + a.w*a.w;
    #pragma unroll
    for (int off = 32; off > 0; off >>= 1) {
        s  += __shfl_xor(s, off);
        ss += __shfl_xor(ss, off);
    }
    if (lane == 0) {
        const float mu = s * (1.0f / 256.0f);
        float2 st;
        st.x = mu;
        st.y = rsqrtf(ss * (1.0f / 256.0f) - mu * mu + 1e-5f);
        ((float2*)stats)[row] = st;
    }
}

// ---------------------------------------------------------------------------
// Split 5 weight matrices into bf16 hi/lo (stacked [5][256][256]).
// Mats 0-3: row PERMUTED within each 32-row head group (even/odd pairing)
// so qkvg's epilogue writes packed dwords while keeping NATURAL output order.
// ---------------------------------------------------------------------------
__global__ __launch_bounds__(256)
void w_prep(const float* __restrict__ W0, const float* __restrict__ W1,
            const float* __restrict__ W2, const float* __restrict__ W3,
            const float* __restrict__ W4, ushort* __restrict__ Whi,
            ushort* __restrict__ Wlo) {
    const float* Ws[5] = {W0, W1, W2, W3, W4};
    const int mat = blockIdx.y;
    const size_t idx = ((size_t)blockIdx.x * 256 + threadIdx.x) * 4;
    const float4 v = *(const float4*)(Ws[mat] + idx);
    ushort4 hi, lo;
    hi.x = f2bf(v.x); lo.x = f2bf(v.x - bf2f(hi.x));
    hi.y = f2bf(v.y); lo.y = f2bf(v.y - bf2f(hi.y));
    hi.z = f2bf(v.z); lo.z = f2bf(v.z - bf2f(hi.z));
    hi.w = f2bf(v.w); lo.w = f2bf(v.w - bf2f(hi.w));
    const int row = (int)(idx >> 8), col = (int)(idx & 255);
    int drow = row;
    if (mat < 4) {
        const int ch = row & 31;
        const int p = (ch & 1) ? 16 + (ch >> 1) : (ch >> 1);
        drow = (row & ~31) | p;
    }
    const size_t o = (size_t)mat * 65536 + (size_t)drow * 256 + col;
    *(ushort4*)(Whi + o) = hi;
    *(ushort4*)(Wlo + o) = lo;
}

// ---------------------------------------------------------------------------
// Mask decode: qflag[q] = seq_pad[q] ? NEG_INF : 0 ; kbias[k] = res_pad[k] ? NEG_INF : 0
// Reference: pad = (seq_pad[q] | res_pad[k]) * NEG_INF — OR => SELECT, not add.
// ---------------------------------------------------------------------------
__global__ void mask_decode_kernel(const unsigned* __restrict__ seq_raw,
                                   const unsigned* __restrict__ res_raw,
                                   float* __restrict__ qflag,
                                   float* __restrict__ kbias) {
    __shared__ unsigned long long sb[4], sf[4];
    __shared__ int enc;
    const int t = threadIdx.x;
    unsigned w = 0;
    if (t < 64)        w = seq_raw[t];
    else if (t < 128)  w = res_raw[t - 64];
    bool bad = (w != 0u) && (w != 1u) && (w != 0x3f800000u);
    bool isf = (w == 0x3f800000u);
    unsigned long long bm = __ballot(bad);
    unsigned long long fm = __ballot(isf);
    const int wid = t >> 6;
    if ((t & 63) == 0) { sb[wid] = bm; sf[wid] = fm; }
    __syncthreads();
    if (t == 0) {
        unsigned long long B = sb[0] | sb[1];
        unsigned long long F = sf[0] | sf[1];
        enc = B ? 2 : (F ? 1 : 0);
    }
    __syncthreads();
    const int e = enc;
    int sv, rv;
    if (e == 2) {
        const unsigned char* sp = (const unsigned char*)seq_raw;
        const unsigned char* rp = (const unsigned char*)res_raw;
        sv = sp[t]; rv = rp[t];
    } else if (e == 1) {
        sv = (((const float*)seq_raw)[t] != 0.0f);
        rv = (((const float*)res_raw)[t] != 0.0f);
    } else {
        sv = (seq_raw[t] != 0u);
        rv = (res_raw[t] != 0u);
    }
    qflag[t] = sv ? NEG_INF : 0.0f;
    kbias[t] = rv ? NEG_INF : 0.0f;
}

// ---------------------------------------------------------------------------
// Fused QKVG GEMM, LN fused into A staging, SOFTWARE-PIPELINED A prefetch:
// next kt's fp32 rows are loaded into registers right after the first
// barrier so MFMA compute covers their latency.
// Block tile: M=64, N=512 (2 matrices), BK=32. grid (2, 512).
// ---------------------------------------------------------------------------
__global__ __launch_bounds__(256, 3)
void qkvg_fused(const float* __restrict__ m, const float* __restrict__ stats,
                const float* __restrict__ lng, const float* __restrict__ lnb,
                const ushort* __restrict__ Whi, const float* __restrict__ bg,
                ushort* __restrict__ qb, ushort* __restrict__ kb,
                ushort* __restrict__ vb, ushort* __restrict__ gbf,
                float qscale) {
    __shared__ __align__(16) ushort Ah[64 * 32];
    __shared__ __align__(16) ushort Al[64 * 32];
    __shared__ __align__(16) ushort Wh[512 * 32];
    const int tid = threadIdx.x, lane = tid & 63, wave = tid >> 6;
    const int li = lane & 15, quad = lane >> 4;
    const int nb = blockIdx.x, m0 = blockIdx.y << 6;
    const int wm = (wave & 1) << 5;         // 0 / 32
    const int wn = (wave >> 1) << 8;        // 0 / 256
    const int mat = nb * 2 + (wave >> 1);   // which weight matrix this wave owns

    const int arow = tid >> 2, aslot = tid & 3;
    const int asw = (arow & 3) ^ ((arow >> 2) & 3);
    const float2 st = ((const float2*)stats)[m0 + arow];
    const float mu = st.x, rs = st.y;
    const float* aprow = m + (size_t)(m0 + arow) * 256 + aslot * 8;

    f32x4 zero = {0.f, 0.f, 0.f, 0.f};
    f32x4 acc[2][16];
    #pragma unroll
    for (int i = 0; i < 2; ++i)
        #pragma unroll
        for (int j = 0; j < 16; ++j) acc[i][j] = zero;

    // prefetch kt=0
    float4 pv0 = *(const float4*)(aprow);
    float4 pv1 = *(const float4*)(aprow + 4);

    for (int kt = 0; kt < 256; kt += 32) {
        #pragma unroll
        for (int i = 0; i < 8; ++i) {
            const int wrow = i * 64 + (tid >> 2);
            const int wsw = (wrow & 3) ^ ((wrow >> 2) & 3);
            const int g = (tid & 3) ^ wsw;
            gload_lds16(Whi + ((size_t)(nb * 512 + wrow) * 256 + kt + g * 8),
                        &Wh[i * 2048 + wave * 512]);
        }
        {
            const float4 g0 = *(const float4*)(lng + kt + aslot * 8);
            const float4 g1 = *(const float4*)(lng + kt + aslot * 8 + 4);
            const float4 b0 = *(const float4*)(lnb + kt + aslot * 8);
            const float4 b1 = *(const float4*)(lnb + kt + aslot * 8 + 4);
            float xs[8] = {pv0.x, pv0.y, pv0.z, pv0.w, pv1.x, pv1.y, pv1.z, pv1.w};
            float gs[8] = {g0.x, g0.y, g0.z, g0.w, g1.x, g1.y, g1.z, g1.w};
            float bs[8] = {b0.x, b0.y, b0.z, b0.w, b1.x, b1.y, b1.z, b1.w};
            bf16x8 hi8, lo8;
            #pragma unroll
            for (int e = 0; e < 8; ++e) {
                const float x = (xs[e] - mu) * rs * gs[e] + bs[e];
                const ushort h = f2bf(x);
                hi8[e] = (short)h;
                lo8[e] = (short)f2bf(x - bf2f(h));
            }
            const int adst = arow * 32 + ((aslot ^ asw) << 3);
            *(bf16x8*)&Ah[adst] = hi8;
            *(bf16x8*)&Al[adst] = lo8;
        }
        __syncthreads();
        // prefetch next kt while MFMAs run
        if (kt + 32 < 256) {
            pv0 = *(const float4*)(aprow + kt + 32);
            pv1 = *(const float4*)(aprow + kt + 36);
        }
        bf16x8 ah[2], al[2];
        #pragma unroll
        for (int mt = 0; mt < 2; ++mt) {
            const int r = wm + mt * 16 + li;
            const int sw = (r & 3) ^ ((r >> 2) & 3);
            const int off = r * 32 + ((quad ^ sw) << 3);
            ah[mt] = *(const bf16x8*)&Ah[off];
            al[mt] = *(const bf16x8*)&Al[off];
        }
        #pragma unroll
        for (int nt = 0; nt < 16; ++nt) {
            const int rn = wn + nt * 16 + li;
            const int sw = (rn & 3) ^ ((rn >> 2) & 3);
            const bf16x8 bh = *(const bf16x8*)&Wh[rn * 32 + ((quad ^ sw) << 3)];
            acc[0][nt] = mfma16(ah[0], bh, acc[0][nt]);
            acc[0][nt] = mfma16(al[0], bh, acc[0][nt]);
            acc[1][nt] = mfma16(ah[1], bh, acc[1][nt]);
            acc[1][nt] = mfma16(al[1], bh, acc[1][nt]);
        }
        __syncthreads();
    }

    // Epilogue: tiles (2h', 2h'+1) = (even, odd) channels of head h'.
    ushort* outp = (mat == 0) ? qb : (mat == 1) ? kb : (mat == 2) ? vb : gbf;
    #pragma unroll
    for (int mt = 0; mt < 2; ++mt) {
        #pragma unroll
        for (int hh = 0; hh < 8; ++hh) {
            const int cE = hh * 32 + 2 * li;
            const float2 bg2 = *(const float2*)(bg + cE);
            #pragma unroll
            for (int r = 0; r < 4; ++r) {
                const int row = m0 + wm + mt * 16 + quad * 4 + r;
                float vE = acc[mt][2 * hh][r];
                float vO = acc[mt][2 * hh + 1][r];
                if (mat == 0) { vE *= qscale; vO *= qscale; }
                if (mat == 3) {
                    vE = 1.0f / (1.0f + __expf(-(vE + bg2.x)));
                    vO = 1.0f / (1.0f + __expf(-(vO + bg2.y)));
                }
                const unsigned u = (unsigned)f2bf(vE) | ((unsigned)f2bf(vO) << 16);
                *(unsigned*)&outp[(size_t)hh * HB + (size_t)row * 32 + 2 * li] = u;
            }
        }
    }
}

// ---------------------------------------------------------------------------
// Attention v6: head-major I/O. LDS only for REUSED data (K swizzled, V^T
// paired) = 32 KB -> 4 blocks/CU. Q/G read directly from global (used once).
// S^T K-row permutation => scores land in PV A-operand layout (no shuffles).
// OR-mask select semantics.
// ---------------------------------------------------------------------------
__global__ __launch_bounds__(256, 4)
void attn2(const ushort* __restrict__ Qb, const ushort* __restrict__ Kb,
           const ushort* __restrict__ Vb, const ushort* __restrict__ Gb,
           const float* __restrict__ qflag, const float* __restrict__ kbias,
           ushort* __restrict__ Ohi, ushort* __restrict__ Olo) {
    __shared__ __align__(16) ushort Kl[8192];   // 16 KB swizzled K
    __shared__ __align__(16) ushort Vt[8192];   // 16 KB paired/swizzled V^T
    const int h = blockIdx.x, s = blockIdx.y;
    const int tid = threadIdx.x, lane = tid & 63, wave = tid >> 6;
    const int li = lane & 15, quad = lane >> 4;
    const size_t base = (size_t)h * HB + (size_t)s * 8192;

    // --- K staging (XOR-swizzled) ---
    const int srow = tid >> 2, slot = tid & 3;
    const int sw0 = (srow & 3) ^ ((srow >> 2) & 3);
    const int gk0 = (slot ^ sw0) << 3;
    #pragma unroll
    for (int i = 0; i < 4; ++i) {
        const int r = i * 64 + srow;
        gload_lds16(Kb + base + (size_t)r * 32 + gk0, &Kl[i * 2048 + wave * 512]);
    }
    // --- V transpose: thread = key. Paired compact layout:
    // Vt[vkb*1024 + (c&1)*512 + vq*128 + (((c>>1)^vsw)<<3) + vj]
    //   = V[key=32vkb+8vq+vj][c]   (tile0 = even channels, tile1 = odd)
    {
        const ushort* vrow = Vb + base + (size_t)tid * 32;
        bf16x8 vv0 = *(const bf16x8*)(vrow);
        bf16x8 vv1 = *(const bf16x8*)(vrow + 8);
        bf16x8 vv2 = *(const bf16x8*)(vrow + 16);
        bf16x8 vv3 = *(const bf16x8*)(vrow + 24);
        const int vkb = tid >> 5, vq = (tid >> 3) & 3, vj = tid & 7;
        const int vsw = (4 * vkb + vq) & 7;
        const int vbase = vkb * 1024 + vq * 128 + vj;
        #pragma unroll
        for (int c = 0; c < 32; ++c) {
            const short val = (c < 8) ? vv0[c & 7] : (c < 16) ? vv1[c & 7]
                            : (c < 24) ? vv2[c & 7] : vv3[c & 7];
            Vt[vbase + (c & 1) * 512 + (((c >> 1) ^ vsw) << 3)] = (ushort)val;
        }
    }
    __syncthreads();

    f32x4 zero = {0.f, 0.f, 0.f, 0.f};

    for (int chunk = 0; chunk < 4; ++chunk) {
        const int q0 = wave * 64 + chunk * 16;     // query base (residue)
        // Q B-frag direct from global: wave covers contiguous 1 KB.
        const bf16x8 qf = *(const bf16x8*)(Qb + base + (size_t)(q0 + li) * 32 + quad * 8);
        // OR-mask select: seq-padded query -> ignore kbias entirely.
        const float kmul = (qflag[q0 + li] != 0.0f) ? 0.0f : 1.0f;

        // S^T tiles with permuted K rows (C/D layout == PV A-layout).
        f32x4 sc[16];
        #pragma unroll
        for (int t = 0; t < 16; ++t) {
            const int kr = (t >> 1) * 32 + ((li >> 2) << 3) + ((t & 1) << 2) + (li & 3);
            const int sw = (kr & 3) ^ ((kr >> 2) & 3);
            const bf16x8 kf = *(const bf16x8*)&Kl[kr * 32 + ((quad ^ sw) << 3)];
            sc[t] = mfma16(kf, qf, zero);
        }
        // sc[t][r] = S^T[key = (t>>1)*32 + 8*quad + 4*(t&1) + r][query = li]
        float mx = -1e30f;
        #pragma unroll
        for (int t = 0; t < 16; ++t) {
            const float4 kb4 = ((const float4*)kbias)[(t >> 1) * 8 + quad * 2 + (t & 1)];
            sc[t][0] += kmul * kb4.x;  sc[t][1] += kmul * kb4.y;
            sc[t][2] += kmul * kb4.z;  sc[t][3] += kmul * kb4.w;
            mx = fmaxf(mx, fmaxf(fmaxf(sc[t][0], sc[t][1]), fmaxf(sc[t][2], sc[t][3])));
        }
        mx = fmaxf(mx, __shfl_xor(mx, 16));
        mx = fmaxf(mx, __shfl_xor(mx, 32));
        float ls = 0.0f;
        #pragma unroll
        for (int t = 0; t < 16; ++t) {
            #pragma unroll
            for (int r = 0; r < 4; ++r) {
                const float p = __expf(sc[t][r] - mx);
                sc[t][r] = p;
                ls += p;
            }
        }
        ls += __shfl_xor(ls, 16);
        ls += __shfl_xor(ls, 32);

        // PV: pf comes straight from this lane's sc — no shuffles.
        f32x4 a0 = zero, a1 = zero;   // a0 -> channel 2li, a1 -> 2li+1
        #pragma unroll
        for (int kbk = 0; kbk < 8; ++kbk) {
            bf16x8 pf;
            pf[0] = (short)f2bf(sc[2 * kbk][0]);
            pf[1] = (short)f2bf(sc[2 * kbk][1]);
            pf[2] = (short)f2bf(sc[2 * kbk][2]);
            pf[3] = (short)f2bf(sc[2 * kbk][3]);
            pf[4] = (short)f2bf(sc[2 * kbk + 1][0]);
            pf[5] = (short)f2bf(sc[2 * kbk + 1][1]);
            pf[6] = (short)f2bf(sc[2 * kbk + 1][2]);
            pf[7] = (short)f2bf(sc[2 * kbk + 1][3]);
            const int vsw = (4 * kbk + quad) & 7;
            const bf16x8 v0 = *(const bf16x8*)&Vt[kbk * 1024 + quad * 128 + ((li ^ vsw) << 3)];
            const bf16x8 v1 = *(const bf16x8*)&Vt[kbk * 1024 + 512 + quad * 128 + ((li ^ vsw) << 3)];
            a0 = mfma16(pf, v0, a0);
            a1 = mfma16(pf, v1, a1);
        }
        // epilogue: dword G global read + dword O stores
        #pragma unroll
        for (int r = 0; r < 4; ++r) {
            const float lsr = __shfl(ls, 4 * quad + r);
            const float inv = 1.0f / lsr;
            const int rowq = q0 + 4 * quad + r;
            const size_t ro = base + (size_t)rowq * 32;
            const unsigned gu = *(const unsigned*)(Gb + ro + 2 * li);
            const float g0 = bf2f((ushort)(gu & 0xFFFFu));
            const float g1 = bf2f((ushort)(gu >> 16));
            const float x0 = a0[r] * inv * g0;
            const float x1 = a1[r] * inv * g1;
            const ushort h0 = f2bf(x0), h1 = f2bf(x1);
            const unsigned uhi = (unsigned)h0 | ((unsigned)h1 << 16);
            const unsigned ulo = (unsigned)f2bf(x0 - bf2f(h0))
                               | ((unsigned)f2bf(x1 - bf2f(h1)) << 16);
            *(unsigned*)&Ohi[ro + 2 * li] = uhi;
            *(unsigned*)&Olo[ro + 2 * li] = ulo;
        }
    }
}

// ---------------------------------------------------------------------------
// Final GEMM: out = (Ohi+Olo) @ (Whi+Wlo)^T + bias, fp32 out.
// A (Ohi/Olo) is HEAD-MAJOR [8][Mrows][32]; k = head*32 + ch (natural order).
// ---------------------------------------------------------------------------
__global__ __launch_bounds__(256)
void gemm_mfma(const ushort* __restrict__ Ahi, const ushort* __restrict__ Alo,
               const ushort* __restrict__ Whi, const ushort* __restrict__ Wlo,
               const float* __restrict__ bias, void* __restrict__ outp,
               float scale, int mode) {
    __shared__ __align__(16) ushort lds[16384];
    const int tid = threadIdx.x;
    const int lane = tid & 63, wave = tid >> 6;
    const int li = lane & 15, quad = lane >> 4;
    const int m0 = blockIdx.y << 7, n0 = blockIdx.x << 7;
    const int wm = (wave >> 1) << 6, wn = (wave & 1) << 6;
    const int srow = tid >> 2, slot = tid & 3;
    const int sw0 = (srow & 3) ^ ((srow >> 2) & 3);
    const int gk0 = (slot ^ sw0) << 3;

    f32x4 zero = {0.f, 0.f, 0.f, 0.f};
    f32x4 acc[4][4];
    #pragma unroll
    for (int i = 0; i < 4; ++i)
        #pragma unroll
        for (int j = 0; j < 4; ++j) acc[i][j] = zero;

    for (int kt = 0; kt < 256; kt += 32) {
        const size_t hplane = (size_t)(kt >> 5) * HB;
        #pragma unroll
        for (int j = 0; j < 2; ++j) {
            const int r = j * 64 + srow;
            const size_t ao = hplane + (size_t)(m0 + r) * 32 + gk0;
            const size_t wo = (size_t)(n0 + r) * 256 + kt + gk0;
            const int lo = j * 2048 + wave * 512;
            gload_lds16(Ahi + ao, &lds[lo]);
            gload_lds16(Alo + ao, &lds[4096 + lo]);
            gload_lds16(Whi + wo, &lds[8192 + lo]);
            gload_lds16(Wlo + wo, &lds[12288 + lo]);
        }
        __syncthreads();
        bf16x8 ah[4], al[4], bh[4], bl[4];
        #pragma unroll
        for (int mt = 0; mt < 4; ++mt) {
            const int r = wm + mt * 16 + li;
            const int sw = (r & 3) ^ ((r >> 2) & 3);
            const int off = r * 32 + ((quad ^ sw) << 3);
            ah[mt] = *(const bf16x8*)&lds[off];
            al[mt] = *(const bf16x8*)&lds[4096 + off];
        }
        #pragma unroll
        for (int nt = 0; nt < 4; ++nt) {
            const int r = wn + nt * 16 + li;
            const int sw = (r & 3) ^ ((r >> 2) & 3);
            const int off = r * 32 + ((quad ^ sw) << 3);
            bh[nt] = *(const bf16x8*)&lds[8192 + off];
            bl[nt] = *(const bf16x8*)&lds[12288 + off];
        }
        #pragma unroll
        for (int mt = 0; mt < 4; ++mt)
            #pragma unroll
            for (int nt = 0; nt < 4; ++nt) {
                acc[mt][nt] = mfma16(ah[mt], bh[nt], acc[mt][nt]);
                acc[mt][nt] = mfma16(al[mt], bh[nt], acc[mt][nt]);
                acc[mt][nt] = mfma16(ah[mt], bl[nt], acc[mt][nt]);
            }
        __syncthreads();
    }

    #pragma unroll
    for (int mt = 0; mt < 4; ++mt) {
        const int rowb = m0 + wm + mt * 16 + quad * 4;
        #pragma unroll
        for (int nt = 0; nt < 4; ++nt) {
            const int col = n0 + wn + nt * 16 + li;
            const float bv = (mode != 0 && bias) ? bias[col] : 0.0f;
            #pragma unroll
            for (int r = 0; r < 4; ++r) {
                const size_t o = (size_t)(rowb + r) * 256 + col;
                const float v = acc[mt][nt][r];
                if (mode == 0) {
                    ((ushort*)outp)[o] = f2bf(v * scale);
                } else if (mode == 1) {
                    const float x = v + bv;
                    ((float*)outp)[o] = 1.0f / (1.0f + __expf(-x));
                } else {
                    ((float*)outp)[o] = v + bv;
                }
            }
        }
    }
}

// ---------------------------------------------------------------------------
// Launch
// ---------------------------------------------------------------------------
extern "C" void kernel_launch(void* const* d_in, const int* in_sizes, int n_in,
                              void* d_out, int out_size, void* d_ws, size_t ws_size,
                              hipStream_t stream) {
    const float* m    = (const float*)d_in[0];
    const unsigned* seqp = (const unsigned*)d_in[1];
    const unsigned* resp = (const unsigned*)d_in[2];
    const float* lng  = (const float*)d_in[3];
    const float* lnb  = (const float*)d_in[4];
    const float* Wq   = (const float*)d_in[5];
    const float* Wk   = (const float*)d_in[6];
    const float* Wv   = (const float*)d_in[7];
    const float* Wg   = (const float*)d_in[8];
    const float* bg   = (const float*)d_in[9];
    const float* Wo   = (const float*)d_in[10];
    const float* bo   = (const float*)d_in[11];
    float* out = (float*)d_out;

    char* p = (char*)d_ws;
    const size_t ABYTES = (size_t)Mrows * Dm * 2;      // 16.78 MB
    float* stats = (float*)p;  p += (size_t)Mrows * 2 * 4;
    ushort* Whi = (ushort*)p;  p += 5 * 65536 * 2;
    ushort* Wlo = (ushort*)p;  p += 5 * 65536 * 2;
    ushort* qb  = (ushort*)p;  p += ABYTES;
    ushort* kb  = (ushort*)p;  p += ABYTES;
    ushort* vb  = (ushort*)p;  p += ABYTES;
    ushort* gbf = (ushort*)p;  p += ABYTES;
    ushort* Ohi = (ushort*)p;  p += ABYTES;
    ushort* Olo = (ushort*)p;  p += ABYTES;
    float* qflag = (float*)p;  p += 1024;
    float* kbias = (float*)p;  p += 1024;

    ln_stats<<<Mrows / 4, 256, 0, stream>>>(m, stats);
    w_prep<<<dim3(64, 5), 256, 0, stream>>>(Wq, Wk, Wv, Wg, Wo, Whi, Wlo);
    mask_decode_kernel<<<1, 256, 0, stream>>>(seqp, resp, qflag, kbias);

    const float qscale = 0.17677669529663687f;   // 1/sqrt(32)
    qkvg_fused<<<dim3(2, 512), 256, 0, stream>>>(m, stats, lng, lnb, Whi, bg,
                                                 qb, kb, vb, gbf, qscale);

    attn2<<<dim3(8, 128), 256, 0, stream>>>(qb, kb, vb, gbf, qflag, kbias, Ohi, Olo);

    gemm_mfma<<<dim3(2, 256), 256, 0, stream>>>(Ohi, Olo, Whi + 4 * 65536, Wlo + 4 * 65536,
                                                bo, out, 1.0f, 2);
}